// Round 1
// baseline (136.290 us; speedup 1.0000x reference)
//
#include <hip/hip_runtime.h>
#include <math.h>

typedef __bf16 bf16;
typedef __bf16 bf16x8 __attribute__((ext_vector_type(8)));
typedef float f32x4 __attribute__((ext_vector_type(4)));

#define BF_N 64
#define T_N 256
#define C_N 512
#define NH_N 8
#define HD_N 64
#define M_N (BF_N * T_N)   // 16384
#define N3C (3 * C_N)      // 1536
#define K_N C_N            // 512

__device__ __forceinline__ void gload_lds16(const void* g, void* l) {
    __builtin_amdgcn_global_load_lds(
        (const __attribute__((address_space(1))) unsigned int*)g,
        (__attribute__((address_space(3))) unsigned int*)l, 16, 0, 0);
}

// ---------------- pass 1a: x fp32 -> bf16 ----------------
__global__ __launch_bounds__(256) void cvt_x_kernel(const float4* __restrict__ x,
                                                    bf16x8* __restrict__ xb, int n8) {
    int idx = blockIdx.x * 256 + threadIdx.x;
    if (idx >= n8) return;
    float4 a = x[idx * 2], b = x[idx * 2 + 1];
    bf16x8 o;
    o[0] = (bf16)a.x; o[1] = (bf16)a.y; o[2] = (bf16)a.z; o[3] = (bf16)a.w;
    o[4] = (bf16)b.x; o[5] = (bf16)b.y; o[6] = (bf16)b.z; o[7] = (bf16)b.w;
    xb[idx] = o;
}

// ---------------- pass 1b: W [512][1536] fp32 -> Wt [1536][512] bf16 ----------------
__global__ __launch_bounds__(256) void transpose_w(const float* __restrict__ W,
                                                   bf16* __restrict__ Wt) {
    __shared__ float tile[32][33];
    int k0 = blockIdx.x * 32;   // 0..511
    int n0 = blockIdx.y * 32;   // 0..1535
    int tx = threadIdx.x & 31, ty = threadIdx.x >> 5;  // ty 0..7
#pragma unroll
    for (int r = 0; r < 4; ++r)
        tile[ty + r * 8][tx] = W[(size_t)(k0 + ty + r * 8) * N3C + n0 + tx];
    __syncthreads();
#pragma unroll
    for (int r = 0; r < 4; ++r)
        Wt[(size_t)(n0 + ty + r * 8) * K_N + k0 + tx] = (bf16)tile[tx][ty + r * 8];
}

// ---------------- pass 2: QKV GEMM (bf16 MFMA, m97 structure) ----------------
// A [16384][512] bf16 row-major, Bt [1536][512] bf16 row-major (= W^T)
// out: q/k/v buffers, each [(b*8+h)*256 + t][64] bf16
__global__ __launch_bounds__(256) void gemm_qkv(const bf16* __restrict__ A,
                                                const bf16* __restrict__ Bt,
                                                const float* __restrict__ bias,
                                                bf16* __restrict__ qb,
                                                bf16* __restrict__ kb,
                                                bf16* __restrict__ vb) {
    __shared__ bf16 As[128][32];  // 8 KiB
    __shared__ bf16 Bs[128][32];  // 8 KiB
    const int tid = threadIdx.x;
    const int w = tid >> 6, lane = tid & 63;
    const int wr = w >> 1, wc = w & 1;
    const int bm = blockIdx.x;  // 0..127
    const int bn = blockIdx.y;  // 0..11

    f32x4 acc[4][4] = {};

    const int lrow = lane >> 2;  // 0..15
    const int lcol = lane & 3;   // 16B unit in a 64B row

    for (int kt = 0; kt < K_N / 32; ++kt) {
        const int kbyte = kt * 64 + lcol * 16;
#pragma unroll
        for (int c = 0; c < 2; ++c) {
            int rA = bm * 128 + w * 32 + c * 16 + lrow;
            gload_lds16((const char*)A + (size_t)rA * (K_N * 2) + kbyte, &As[w * 32 + c * 16][0]);
            int rB = bn * 128 + w * 32 + c * 16 + lrow;
            gload_lds16((const char*)Bt + (size_t)rB * (K_N * 2) + kbyte, &Bs[w * 32 + c * 16][0]);
        }
        __syncthreads();
        bf16x8 af[4], bfr[4];
        const int koff = (lane >> 4) * 8;
#pragma unroll
        for (int m = 0; m < 4; ++m)
            af[m] = *(const bf16x8*)&As[wr * 64 + m * 16 + (lane & 15)][koff];
#pragma unroll
        for (int n = 0; n < 4; ++n)
            bfr[n] = *(const bf16x8*)&Bs[wc * 64 + n * 16 + (lane & 15)][koff];
#pragma unroll
        for (int m = 0; m < 4; ++m)
#pragma unroll
            for (int n = 0; n < 4; ++n)
                acc[m][n] = __builtin_amdgcn_mfma_f32_16x16x32_bf16(af[m], bfr[n], acc[m][n], 0, 0, 0);
        __syncthreads();
    }

    // epilogue: + bias, scatter into q/k/v per-(b,h) layout, bf16
#pragma unroll
    for (int n = 0; n < 4; ++n) {
        int gcol = bn * 128 + wc * 64 + n * 16 + (lane & 15);
        float bv = bias[gcol];
        int h = gcol / 192;
        int r = gcol - h * 192;
        int sel = r >> 6;
        int d = r & 63;
        bf16* dst = sel == 0 ? qb : (sel == 1 ? kb : vb);
#pragma unroll
        for (int m = 0; m < 4; ++m) {
#pragma unroll
            for (int j = 0; j < 4; ++j) {
                int grow = bm * 128 + wr * 64 + m * 16 + (lane >> 4) * 4 + j;
                int b_ = grow >> 8, t = grow & 255;
                size_t off = (((size_t)b_ * NH_N + h) * T_N + t) * HD_N + d;
                dst[off] = (bf16)(acc[m][n][j] + bv);
            }
        }
    }
}

// ---------------- pass 3: banded causal attention ----------------
// one block per (b,h); thread i = query i; keys j in [i-31, i]
__global__ __launch_bounds__(256) void attn_kernel(const bf16* __restrict__ qb,
                                                   const bf16* __restrict__ kb,
                                                   const bf16* __restrict__ vb,
                                                   const float* __restrict__ pe,
                                                   float* __restrict__ out) {
    __shared__ bf16 Ks[T_N * 64];  // 32 KiB, rows 128B, 16B-unit XOR swizzle
    __shared__ bf16 Vs[T_N * 64];  // 32 KiB
    const int bh = blockIdx.x;  // b*8 + h
    const int h = bh & 7, b = bh >> 3;
    const int i = threadIdx.x;  // 0..255

    const size_t rowo = ((size_t)bh * T_N + i) * HD_N;
    {
        const uint4* kr = (const uint4*)(kb + rowo);
        const uint4* vr = (const uint4*)(vb + rowo);
#pragma unroll
        for (int u = 0; u < 8; ++u) {
            int su = (u ^ (i & 7)) * 8;
            *(uint4*)&Ks[i * 64 + su] = kr[u];
            *(uint4*)&Vs[i * 64 + su] = vr[u];
        }
    }
    float qf[64];
    {
        const bf16x8* qr = (const bf16x8*)(qb + rowo);
#pragma unroll
        for (int u = 0; u < 8; ++u) {
            bf16x8 qv = qr[u];
#pragma unroll
            for (int e = 0; e < 8; ++e) qf[u * 8 + e] = (float)qv[e];
        }
    }
    __syncthreads();

    float s[32];
#pragma unroll
    for (int o = 0; o < 32; ++o) {
        int key = i - 31 + o;
        int krow = key < 0 ? 0 : key;
        float dot = 0.f;
#pragma unroll
        for (int u = 0; u < 8; ++u) {
            bf16x8 kv = *(const bf16x8*)&Ks[krow * 64 + ((u ^ (krow & 7)) * 8)];
#pragma unroll
            for (int e = 0; e < 8; ++e) dot += qf[u * 8 + e] * (float)kv[e];
        }
        // bias: pe[h][o] (o = 31 - (i-key)); invalid keys -> -inf
        s[o] = (key >= 0) ? dot * 0.125f + pe[h * 32 + o] : -INFINITY;
    }

    float mx = s[31];  // o=31 (key=i) always valid
#pragma unroll
    for (int o = 0; o < 31; ++o) mx = fmaxf(mx, s[o]);
    float l = 0.f;
#pragma unroll
    for (int o = 0; o < 32; ++o) {
        float p = __expf(s[o] - mx);  // exp(-inf)=0 masks invalid
        s[o] = p;
        l += p;
    }
    float inv = 1.0f / l;

    float oacc[64];
#pragma unroll
    for (int d = 0; d < 64; ++d) oacc[d] = 0.f;
#pragma unroll
    for (int o = 0; o < 32; ++o) {
        int key = i - 31 + o;
        int vrow = key < 0 ? 0 : key;
        float p = s[o];
#pragma unroll
        for (int u = 0; u < 8; ++u) {
            bf16x8 vv = *(const bf16x8*)&Vs[vrow * 64 + ((u ^ (vrow & 7)) * 8)];
#pragma unroll
            for (int e = 0; e < 8; ++e) oacc[u * 8 + e] += p * (float)vv[e];
        }
    }

    float* op = out + ((size_t)(b * T_N + i)) * C_N + h * HD_N;
#pragma unroll
    for (int u = 0; u < 16; ++u) {
        float4 v4;
        v4.x = oacc[u * 4 + 0] * inv;
        v4.y = oacc[u * 4 + 1] * inv;
        v4.z = oacc[u * 4 + 2] * inv;
        v4.w = oacc[u * 4 + 3] * inv;
        *(float4*)(op + u * 4) = v4;
    }
}

extern "C" void kernel_launch(void* const* d_in, const int* in_sizes, int n_in,
                              void* d_out, int out_size, void* d_ws, size_t ws_size,
                              hipStream_t stream) {
    const float* x = (const float*)d_in[0];     // [64,256,512]
    const float* pe = (const float*)d_in[1];    // [8,32]
    const float* W = (const float*)d_in[2];     // [512,1536]
    const float* bq = (const float*)d_in[3];    // [1536]
    float* out = (float*)d_out;                 // [64,256,512]
    char* ws = (char*)d_ws;

    // workspace layout (bytes):
    bf16* qb = (bf16*)(ws + 0);          // 16 MiB  [(b*8+h)*256+t][64]
    bf16* kb = (bf16*)(ws + 16777216);   // 16 MiB
    bf16* vb = (bf16*)(ws + 33554432);   // 16 MiB
    bf16* xb = (bf16*)(ws + 50331648);   // 16 MiB  [16384][512]
    bf16* wt = (bf16*)(ws + 67108864);   // 1.5 MiB [1536][512]

    cvt_x_kernel<<<4096, 256, 0, stream>>>((const float4*)x, (bf16x8*)xb, M_N * K_N / 8);
    transpose_w<<<dim3(16, 48), 256, 0, stream>>>(W, wt);
    gemm_qkv<<<dim3(128, 12), 256, 0, stream>>>(xb, wt, bq, qb, kb, vb);
    attn_kernel<<<512, 256, 0, stream>>>(qb, kb, vb, pe, out);
}

// Round 2
// 81.675 us; speedup vs baseline: 1.6687x; 1.6687x over previous
//
#include <hip/hip_runtime.h>
#include <math.h>

typedef __bf16 bf16;
typedef __bf16 bf16x8 __attribute__((ext_vector_type(8)));
typedef float f32x4 __attribute__((ext_vector_type(4)));

#define BF_N 64
#define T_N 256
#define C_N 512
#define NH_N 8
#define HD_N 64
#define M_N (BF_N * T_N)   // 16384
#define N3C (3 * C_N)      // 1536
#define K_N C_N            // 512

__device__ __forceinline__ void gload_lds16(const void* g, void* l) {
    __builtin_amdgcn_global_load_lds(
        (const __attribute__((address_space(1))) unsigned int*)g,
        (__attribute__((address_space(3))) unsigned int*)l, 16, 0, 0);
}

// ---------------- pass 1a: x fp32 -> bf16 ----------------
__global__ __launch_bounds__(256) void cvt_x_kernel(const float4* __restrict__ x,
                                                    bf16x8* __restrict__ xb, int n8) {
    int idx = blockIdx.x * 256 + threadIdx.x;
    if (idx >= n8) return;
    float4 a = x[idx * 2], b = x[idx * 2 + 1];
    bf16x8 o;
    o[0] = (bf16)a.x; o[1] = (bf16)a.y; o[2] = (bf16)a.z; o[3] = (bf16)a.w;
    o[4] = (bf16)b.x; o[5] = (bf16)b.y; o[6] = (bf16)b.z; o[7] = (bf16)b.w;
    xb[idx] = o;
}

// ---------------- pass 1b: W [512][1536] fp32 -> Wt [1536][512] bf16 ----------------
__global__ __launch_bounds__(256) void transpose_w(const float* __restrict__ W,
                                                   bf16* __restrict__ Wt) {
    __shared__ float tile[32][33];
    int k0 = blockIdx.x * 32;   // 0..511
    int n0 = blockIdx.y * 32;   // 0..1535
    int tx = threadIdx.x & 31, ty = threadIdx.x >> 5;  // ty 0..7
#pragma unroll
    for (int r = 0; r < 4; ++r)
        tile[ty + r * 8][tx] = W[(size_t)(k0 + ty + r * 8) * N3C + n0 + tx];
    __syncthreads();
#pragma unroll
    for (int r = 0; r < 4; ++r)
        Wt[(size_t)(n0 + ty + r * 8) * K_N + k0 + tx] = (bf16)tile[tx][ty + r * 8];
}

// ---------------- pass 2: QKV GEMM (bf16 MFMA, m97 structure) ----------------
// A [16384][512] bf16 row-major, Bt [1536][512] bf16 row-major (= W^T)
// out: q [bh][t][64], k [bh][t][64], v TRANSPOSED [bh][d][t]  (bh = b*8+h)
__global__ __launch_bounds__(256) void gemm_qkv(const bf16* __restrict__ A,
                                                const bf16* __restrict__ Bt,
                                                const float* __restrict__ bias,
                                                bf16* __restrict__ qb,
                                                bf16* __restrict__ kb,
                                                bf16* __restrict__ vbT) {
    __shared__ bf16 As[128][32];  // 8 KiB
    __shared__ bf16 Bs[128][32];  // 8 KiB
    const int tid = threadIdx.x;
    const int w = tid >> 6, lane = tid & 63;
    const int wr = w >> 1, wc = w & 1;
    const int bm = blockIdx.x;  // 0..127
    const int bn = blockIdx.y;  // 0..11

    f32x4 acc[4][4] = {};

    const int lrow = lane >> 2;  // 0..15
    const int lcol = lane & 3;   // 16B unit in a 64B row

    for (int kt = 0; kt < K_N / 32; ++kt) {
        const int kbyte = kt * 64 + lcol * 16;
#pragma unroll
        for (int c = 0; c < 2; ++c) {
            int rA = bm * 128 + w * 32 + c * 16 + lrow;
            gload_lds16((const char*)A + (size_t)rA * (K_N * 2) + kbyte, &As[w * 32 + c * 16][0]);
            int rB = bn * 128 + w * 32 + c * 16 + lrow;
            gload_lds16((const char*)Bt + (size_t)rB * (K_N * 2) + kbyte, &Bs[w * 32 + c * 16][0]);
        }
        __syncthreads();
        bf16x8 af[4], bfr[4];
        const int koff = (lane >> 4) * 8;
#pragma unroll
        for (int m = 0; m < 4; ++m)
            af[m] = *(const bf16x8*)&As[wr * 64 + m * 16 + (lane & 15)][koff];
#pragma unroll
        for (int n = 0; n < 4; ++n)
            bfr[n] = *(const bf16x8*)&Bs[wc * 64 + n * 16 + (lane & 15)][koff];
#pragma unroll
        for (int m = 0; m < 4; ++m)
#pragma unroll
            for (int n = 0; n < 4; ++n)
                acc[m][n] = __builtin_amdgcn_mfma_f32_16x16x32_bf16(af[m], bfr[n], acc[m][n], 0, 0, 0);
        __syncthreads();
    }

    // epilogue: + bias, scatter into q/k/vT per-(b,h) layout, bf16
#pragma unroll
    for (int n = 0; n < 4; ++n) {
        int gcol = bn * 128 + wc * 64 + n * 16 + (lane & 15);
        float bv = bias[gcol];
        int h = gcol / 192;
        int r = gcol - h * 192;
        int sel = r >> 6;
        int d = r & 63;
#pragma unroll
        for (int m = 0; m < 4; ++m) {
#pragma unroll
            for (int j = 0; j < 4; ++j) {
                int grow = bm * 128 + wr * 64 + m * 16 + (lane >> 4) * 4 + j;
                int b_ = grow >> 8, t = grow & 255;
                int bh = b_ * NH_N + h;
                float val = acc[m][n][j] + bv;
                if (sel == 0) {
                    qb[(((size_t)bh) * T_N + t) * HD_N + d] = (bf16)val;
                } else if (sel == 1) {
                    kb[(((size_t)bh) * T_N + t) * HD_N + d] = (bf16)val;
                } else {
                    vbT[(((size_t)bh) * HD_N + d) * T_N + t] = (bf16)val;
                }
            }
        }
    }
}

// ---------------- pass 3: banded causal attention via MFMA ----------------
// grid = 1024 blocks: blk = bh*2 + half; 4 waves/block; wave w owns the
// 32-query tile starting at q0 = half*128 + w*32. Key window: [q0-32, q0+32).
__global__ __launch_bounds__(256) void attn_mfma(const bf16* __restrict__ qb,
                                                 const bf16* __restrict__ kb,
                                                 const bf16* __restrict__ vbT,
                                                 const float* __restrict__ pe,
                                                 float* __restrict__ out) {
    __shared__ bf16 Pbuf[4][32 * 64];  // 4 KiB per wave, XOR-swizzled 16B units
    const int blk = blockIdx.x;
    const int bh = blk >> 1, half = blk & 1;
    const int h = bh & 7, b = bh >> 3;
    const int tid = threadIdx.x;
    const int w = tid >> 6, lane = tid & 63;
    const int lo = lane & 15, g = lane >> 4;
    bf16* P = &Pbuf[w][0];

    const float pev = pe[h * 32 + (lane & 31)];  // lane r holds pe[h][r&31]

    const int q0 = half * 128 + w * 32;
    const int k0 = q0 - 32;

    const bf16* Qbase = qb + (size_t)bh * T_N * HD_N;
    const bf16* Kbase = kb + (size_t)bh * T_N * HD_N;
    const bf16* Vbase = vbT + (size_t)bh * HD_N * T_N;

    // Q fragments: A[row = q0+qt*16+lo][d-chunk c]
    bf16x8 Qf[2][2];
#pragma unroll
    for (int qt = 0; qt < 2; ++qt)
#pragma unroll
        for (int c = 0; c < 2; ++c)
            Qf[qt][c] = *(const bf16x8*)(Qbase + (size_t)(q0 + qt * 16 + lo) * HD_N + c * 32 + g * 8);

    // QK^T: S[q][key], 2 q-tiles x 4 key-tiles
    f32x4 sc[2][4] = {};
#pragma unroll
    for (int kt = 0; kt < 4; ++kt) {
        int krow = k0 + kt * 16 + lo;
        if (krow < 0) krow = 0;  // masked later
        bf16x8 Kf0 = *(const bf16x8*)(Kbase + (size_t)krow * HD_N + g * 8);
        bf16x8 Kf1 = *(const bf16x8*)(Kbase + (size_t)krow * HD_N + 32 + g * 8);
#pragma unroll
        for (int qt = 0; qt < 2; ++qt) {
            sc[qt][kt] = __builtin_amdgcn_mfma_f32_16x16x32_bf16(Qf[qt][0], Kf0, sc[qt][kt], 0, 0, 0);
            sc[qt][kt] = __builtin_amdgcn_mfma_f32_16x16x32_bf16(Qf[qt][1], Kf1, sc[qt][kt], 0, 0, 0);
        }
    }

    // bias + mask (lane holds S[q = qt*16+g*4+j][key = kt*16+lo], both tile-relative)
#pragma unroll
    for (int qt = 0; qt < 2; ++qt)
#pragma unroll
        for (int kt = 0; kt < 4; ++kt) {
            int key = k0 + kt * 16 + lo;  // absolute, unclamped
#pragma unroll
            for (int j = 0; j < 4; ++j) {
                int dqk = 32 + (qt - kt) * 16 + g * 4 + j - lo;  // q - key
                float bv = __shfl(pev, (31 - dqk) & 63);
                bool valid = (dqk >= 0) && (dqk <= 31) && (key >= 0);
                sc[qt][kt][j] = valid ? sc[qt][kt][j] * 0.125f + bv : -INFINITY;
            }
        }

    // row softmax: in-lane over 4 kt regs + butterfly over lane bits 0..3
    float inv_[2][4];
#pragma unroll
    for (int qt = 0; qt < 2; ++qt)
#pragma unroll
        for (int j = 0; j < 4; ++j) {
            float m = fmaxf(fmaxf(sc[qt][0][j], sc[qt][1][j]),
                            fmaxf(sc[qt][2][j], sc[qt][3][j]));
            m = fmaxf(m, __shfl_xor(m, 1));
            m = fmaxf(m, __shfl_xor(m, 2));
            m = fmaxf(m, __shfl_xor(m, 4));
            m = fmaxf(m, __shfl_xor(m, 8));
            float s = 0.f;
#pragma unroll
            for (int kt = 0; kt < 4; ++kt) {
                float p = __expf(sc[qt][kt][j] - m);
                sc[qt][kt][j] = p;
                s += p;
            }
            s += __shfl_xor(s, 1);
            s += __shfl_xor(s, 2);
            s += __shfl_xor(s, 4);
            s += __shfl_xor(s, 8);
            inv_[qt][j] = 1.0f / s;
        }

    // P -> LDS (bf16, swizzled: unit = (key>>3) ^ (q&7))
#pragma unroll
    for (int qt = 0; qt < 2; ++qt)
#pragma unroll
        for (int kt = 0; kt < 4; ++kt)
#pragma unroll
            for (int j = 0; j < 4; ++j) {
                int q = qt * 16 + g * 4 + j;
                int key = kt * 16 + lo;
                P[q * 64 + (((key >> 3) ^ (q & 7)) * 8) + (key & 7)] = (bf16)sc[qt][kt][j];
            }

    // PV: O[q][d] = sum_key P[q][key] * Vt[d][key]
    f32x4 oa[2][4] = {};
#pragma unroll
    for (int c = 0; c < 2; ++c) {
        bf16x8 Pa[2];
#pragma unroll
        for (int ot = 0; ot < 2; ++ot) {
            int qp = ot * 16 + lo;
            int su = (c * 4 + g) ^ (qp & 7);
            Pa[ot] = *(const bf16x8*)&P[qp * 64 + su * 8];
        }
        int ks = k0 + c * 32 + g * 8;
        if (ks < 0) ks = 0;  // corresponding P entries are 0
#pragma unroll
        for (int dt = 0; dt < 4; ++dt) {
            bf16x8 Vf = *(const bf16x8*)(Vbase + (size_t)(dt * 16 + lo) * T_N + ks);
#pragma unroll
            for (int ot = 0; ot < 2; ++ot)
                oa[ot][dt] = __builtin_amdgcn_mfma_f32_16x16x32_bf16(Pa[ot], Vf, oa[ot][dt], 0, 0, 0);
        }
    }

    // write out (fp32), normalized
#pragma unroll
    for (int ot = 0; ot < 2; ++ot)
#pragma unroll
        for (int dt = 0; dt < 4; ++dt)
#pragma unroll
            for (int j = 0; j < 4; ++j) {
                int q = q0 + ot * 16 + g * 4 + j;
                out[((size_t)(b * T_N + q)) * C_N + h * HD_N + dt * 16 + lo] =
                    oa[ot][dt][j] * inv_[ot][j];
            }
}

extern "C" void kernel_launch(void* const* d_in, const int* in_sizes, int n_in,
                              void* d_out, int out_size, void* d_ws, size_t ws_size,
                              hipStream_t stream) {
    const float* x = (const float*)d_in[0];     // [64,256,512]
    const float* pe = (const float*)d_in[1];    // [8,32]
    const float* W = (const float*)d_in[2];     // [512,1536]
    const float* bq = (const float*)d_in[3];    // [1536]
    float* out = (float*)d_out;                 // [64,256,512]
    char* ws = (char*)d_ws;

    // workspace layout (bytes):
    bf16* qb = (bf16*)(ws + 0);          // 16 MiB  [bh][t][64]
    bf16* kb = (bf16*)(ws + 16777216);   // 16 MiB  [bh][t][64]
    bf16* vbT = (bf16*)(ws + 33554432);  // 16 MiB  [bh][d][t]  (transposed)
    bf16* xb = (bf16*)(ws + 50331648);   // 16 MiB  [16384][512]
    bf16* wt = (bf16*)(ws + 67108864);   // 1.5 MiB [1536][512]

    cvt_x_kernel<<<4096, 256, 0, stream>>>((const float4*)x, (bf16x8*)xb, M_N * K_N / 8);
    transpose_w<<<dim3(16, 48), 256, 0, stream>>>(W, wt);
    gemm_qkv<<<dim3(128, 12), 256, 0, stream>>>(xb, wt, bq, qb, kb, vbT);
    attn_mfma<<<1024, 256, 0, stream>>>(qb, kb, vbT, pe, out);
}

// Round 3
// 57.035 us; speedup vs baseline: 2.3896x; 1.4320x over previous
//
#include <hip/hip_runtime.h>
#include <math.h>

typedef __bf16 bf16;
typedef __bf16 bf16x4 __attribute__((ext_vector_type(4)));
typedef __bf16 bf16x8 __attribute__((ext_vector_type(8)));
typedef float f32x4 __attribute__((ext_vector_type(4)));

#define BF_N 64
#define T_N 256
#define C_N 512
#define NH_N 8
#define HD_N 64
#define M_N (BF_N * T_N)   // 16384
#define N3C (3 * C_N)      // 1536
#define K_N C_N            // 512

__device__ __forceinline__ void gload_lds16(const void* g, void* l) {
    __builtin_amdgcn_global_load_lds(
        (const __attribute__((address_space(1))) unsigned int*)g,
        (__attribute__((address_space(3))) unsigned int*)l, 16, 0, 0);
}

// ---------------- pass 1a: x fp32 -> bf16 ----------------
__global__ __launch_bounds__(256) void cvt_x_kernel(const float4* __restrict__ x,
                                                    bf16x8* __restrict__ xb, int n8) {
    int idx = blockIdx.x * 256 + threadIdx.x;
    if (idx >= n8) return;
    float4 a = x[idx * 2], b = x[idx * 2 + 1];
    bf16x8 o;
    o[0] = (bf16)a.x; o[1] = (bf16)a.y; o[2] = (bf16)a.z; o[3] = (bf16)a.w;
    o[4] = (bf16)b.x; o[5] = (bf16)b.y; o[6] = (bf16)b.z; o[7] = (bf16)b.w;
    xb[idx] = o;
}

// ---------------- pass 1b: W [512][1536] fp32 -> Wt [1536][512] bf16 ----------------
__global__ __launch_bounds__(256) void transpose_w(const float* __restrict__ W,
                                                   bf16* __restrict__ Wt) {
    __shared__ float tile[32][33];
    int k0 = blockIdx.x * 32;   // 0..511
    int n0 = blockIdx.y * 32;   // 0..1535
    int tx = threadIdx.x & 31, ty = threadIdx.x >> 5;  // ty 0..7
#pragma unroll
    for (int r = 0; r < 4; ++r)
        tile[ty + r * 8][tx] = W[(size_t)(k0 + ty + r * 8) * N3C + n0 + tx];
    __syncthreads();
#pragma unroll
    for (int r = 0; r < 4; ++r)
        Wt[(size_t)(n0 + ty + r * 8) * K_N + k0 + tx] = (bf16)tile[tx][ty + r * 8];
}

// ---------------- pass 2: fused QKV-GEMM + banded attention, one block per (b,h) ----
// LDS map (128 KiB):
//   GEMM phase : A0@0(32K) A1@32K(32K) B0@64K(24K) B1@88K(24K)
//   attn phase : Qs@0(32K) Ks@32K(32K) Vt@64K(32K) P@96K+w*4K(32K)
// All 2D LDS tiles use 16B-unit XOR swizzle: unit' = unit ^ (row & 7).
// global_load_lds writes linearly, so the swizzle is applied by pre-swizzling
// the per-lane GLOBAL source address (rule #21).
__global__ __launch_bounds__(512, 1) void fused_qkv_attn(
    const bf16* __restrict__ xb,   // [64][256][512]
    const bf16* __restrict__ wt,   // [1536][512] = W^T
    const float* __restrict__ bias,
    const float* __restrict__ pe,
    float* __restrict__ out) {
    __shared__ __align__(16) char smem[131072];
    const int blk = blockIdx.x;
    const int b = blk & 63, h = blk >> 6;       // same-b blocks share an XCD (blk%8==b%8)
    const int tid = threadIdx.x;
    const int w = tid >> 6, lane = tid & 63;
    const int lo = lane & 15, g = lane >> 4;
    const int wr = w >> 2, wc = w & 3;          // 2(M=128) x 4(N=48) wave grid

    const bf16* xbb = xb + (size_t)b * T_N * C_N;
    const bf16* wth = wt + (size_t)h * 192 * K_N;

    const int r8 = w * 8 + (lane >> 3);  // row within a 64-row staging issue
    const int uu = lane & 7;             // 16B unit within a 128B row

    auto stage = [&](int buf, int kt) {
        char* Ab = smem + buf * 32768;
        char* Bb = smem + 65536 + buf * 24576;
#pragma unroll
        for (int i = 0; i < 4; ++i) {
            int row = i * 64 + r8;
            int su = uu ^ (row & 7);
            gload_lds16(xbb + (size_t)row * K_N + kt * 64 + su * 8,
                        Ab + i * 8192 + w * 1024);
        }
#pragma unroll
        for (int j = 0; j < 3; ++j) {
            int row = j * 64 + r8;
            int su = uu ^ (row & 7);
            gload_lds16(wth + (size_t)row * K_N + kt * 64 + su * 8,
                        Bb + j * 8192 + w * 1024);
        }
    };

    f32x4 acc[8][3] = {};

    stage(0, 0);
    __syncthreads();
    for (int kt = 0; kt < 8; ++kt) {
        if (kt < 7) stage((kt + 1) & 1, kt + 1);  // issue-early prefetch
        const char* Ab = smem + (kt & 1) * 32768;
        const char* Bb = smem + 65536 + (kt & 1) * 24576;
#pragma unroll
        for (int ks = 0; ks < 2; ++ks) {
            bf16x8 af[8], bfr[3];
#pragma unroll
            for (int m = 0; m < 8; ++m) {
                int row = wr * 128 + m * 16 + lo;
                int u = (ks * 4 + g) ^ (row & 7);
                af[m] = *(const bf16x8*)(Ab + row * 128 + u * 16);
            }
#pragma unroll
            for (int n = 0; n < 3; ++n) {
                int row = wc * 48 + n * 16 + lo;
                int u = (ks * 4 + g) ^ (row & 7);
                bfr[n] = *(const bf16x8*)(Bb + row * 128 + u * 16);
            }
#pragma unroll
            for (int m = 0; m < 8; ++m)
#pragma unroll
                for (int n = 0; n < 3; ++n)
                    acc[m][n] = __builtin_amdgcn_mfma_f32_16x16x32_bf16(af[m], bfr[n], acc[m][n], 0, 0, 0);
        }
        __syncthreads();
    }

    // ---- epilogue: acc(+bias) -> LDS q/k/vT (bf16, swizzled) ----
    float bv[3];
#pragma unroll
    for (int n = 0; n < 3; ++n)
        bv[n] = bias[h * 192 + wc * 48 + n * 16 + lo];

#pragma unroll
    for (int m = 0; m < 8; ++m) {
        int rowb = wr * 128 + m * 16 + g * 4;
#pragma unroll
        for (int n = 0; n < 3; ++n) {
            int col = wc * 48 + n * 16 + lo;  // wave-uniform region per (wc,n)
            if (col < 128) {
                char* base = smem + (col < 64 ? 0 : 32768);
                int d = col & 63;
#pragma unroll
                for (int j = 0; j < 4; ++j) {
                    int row = rowb + j;
                    int u = (d >> 3) ^ (row & 7);
                    *(bf16*)(base + row * 128 + u * 16 + (d & 7) * 2) =
                        (bf16)(acc[m][n][j] + bv[n]);
                }
            } else {
                int d = col - 128;
                bf16x4 pk;
#pragma unroll
                for (int j = 0; j < 4; ++j) pk[j] = (bf16)(acc[m][n][j] + bv[n]);
                int u = (rowb >> 3) ^ (d & 7);
                *(bf16x4*)(smem + 65536 + d * 512 + u * 16 + ((rowb >> 2) & 1) * 8) = pk;
            }
        }
    }
    __syncthreads();

    // ---- banded attention: wave w owns q rows [w*32, w*32+32) ----
    bf16* P = (bf16*)(smem + 98304 + w * 4096);
    const float pev = pe[h * 32 + (lane & 31)];
    const int q0 = w * 32;
    const int k0 = q0 - 32;

    bf16x8 Qf[2][2];
#pragma unroll
    for (int qt = 0; qt < 2; ++qt)
#pragma unroll
        for (int c = 0; c < 2; ++c) {
            int row = q0 + qt * 16 + lo;
            int u = (c * 4 + g) ^ (row & 7);
            Qf[qt][c] = *(const bf16x8*)(smem + row * 128 + u * 16);
        }

    f32x4 sc[2][4] = {};
#pragma unroll
    for (int kt4 = 0; kt4 < 4; ++kt4) {
        int krow = k0 + kt4 * 16 + lo;
        if (krow < 0) krow = 0;  // masked later
        int u0 = g ^ (krow & 7);
        int u1 = (4 + g) ^ (krow & 7);
        bf16x8 Kf0 = *(const bf16x8*)(smem + 32768 + krow * 128 + u0 * 16);
        bf16x8 Kf1 = *(const bf16x8*)(smem + 32768 + krow * 128 + u1 * 16);
#pragma unroll
        for (int qt = 0; qt < 2; ++qt) {
            sc[qt][kt4] = __builtin_amdgcn_mfma_f32_16x16x32_bf16(Qf[qt][0], Kf0, sc[qt][kt4], 0, 0, 0);
            sc[qt][kt4] = __builtin_amdgcn_mfma_f32_16x16x32_bf16(Qf[qt][1], Kf1, sc[qt][kt4], 0, 0, 0);
        }
    }

    // bias + mask
#pragma unroll
    for (int qt = 0; qt < 2; ++qt)
#pragma unroll
        for (int kt4 = 0; kt4 < 4; ++kt4) {
            int key = k0 + kt4 * 16 + lo;  // absolute, unclamped
#pragma unroll
            for (int j = 0; j < 4; ++j) {
                int dqk = 32 + (qt - kt4) * 16 + g * 4 + j - lo;  // q - key
                float bvv = __shfl(pev, (31 - dqk) & 63);
                bool valid = (dqk >= 0) && (dqk <= 31) && (key >= 0);
                sc[qt][kt4][j] = valid ? sc[qt][kt4][j] * 0.125f + bvv : -INFINITY;
            }
        }

    // row softmax
    float inv_[2][4];
#pragma unroll
    for (int qt = 0; qt < 2; ++qt)
#pragma unroll
        for (int j = 0; j < 4; ++j) {
            float m = fmaxf(fmaxf(sc[qt][0][j], sc[qt][1][j]),
                            fmaxf(sc[qt][2][j], sc[qt][3][j]));
            m = fmaxf(m, __shfl_xor(m, 1));
            m = fmaxf(m, __shfl_xor(m, 2));
            m = fmaxf(m, __shfl_xor(m, 4));
            m = fmaxf(m, __shfl_xor(m, 8));
            float s = 0.f;
#pragma unroll
            for (int kt4 = 0; kt4 < 4; ++kt4) {
                float p = __expf(sc[qt][kt4][j] - m);
                sc[qt][kt4][j] = p;
                s += p;
            }
            s += __shfl_xor(s, 1);
            s += __shfl_xor(s, 2);
            s += __shfl_xor(s, 4);
            s += __shfl_xor(s, 8);
            inv_[qt][j] = 1.0f / s;
        }

    // P -> LDS (bf16, swizzled)
#pragma unroll
    for (int qt = 0; qt < 2; ++qt)
#pragma unroll
        for (int kt4 = 0; kt4 < 4; ++kt4)
#pragma unroll
            for (int j = 0; j < 4; ++j) {
                int q = qt * 16 + g * 4 + j;
                int key = kt4 * 16 + lo;
                P[q * 64 + (((key >> 3) ^ (q & 7)) * 8) + (key & 7)] = (bf16)sc[qt][kt4][j];
            }

    // PV: O[q][d] = sum_key P[q][key] * Vt[d][key]
    f32x4 oa[2][4] = {};
#pragma unroll
    for (int c = 0; c < 2; ++c) {
        bf16x8 Pa[2];
#pragma unroll
        for (int ot = 0; ot < 2; ++ot) {
            int qp = ot * 16 + lo;
            int su = (c * 4 + g) ^ (qp & 7);
            Pa[ot] = *(const bf16x8*)&P[qp * 64 + su * 8];
        }
        int ks = k0 + c * 32 + g * 8;
        if (ks < 0) ks = 0;  // corresponding P entries are 0
#pragma unroll
        for (int dt = 0; dt < 4; ++dt) {
            int d = dt * 16 + lo;
            int u = ((ks >> 3) ^ (d & 7));
            bf16x8 Vf = *(const bf16x8*)(smem + 65536 + d * 512 + u * 16);
#pragma unroll
            for (int ot = 0; ot < 2; ++ot)
                oa[ot][dt] = __builtin_amdgcn_mfma_f32_16x16x32_bf16(Pa[ot], Vf, oa[ot][dt], 0, 0, 0);
        }
    }

    // write out (fp32), normalized
#pragma unroll
    for (int ot = 0; ot < 2; ++ot)
#pragma unroll
        for (int dt = 0; dt < 4; ++dt)
#pragma unroll
            for (int j = 0; j < 4; ++j) {
                int q = q0 + ot * 16 + g * 4 + j;
                out[((size_t)(b * T_N + q)) * C_N + h * HD_N + dt * 16 + lo] =
                    oa[ot][dt][j] * inv_[ot][j];
            }
}

extern "C" void kernel_launch(void* const* d_in, const int* in_sizes, int n_in,
                              void* d_out, int out_size, void* d_ws, size_t ws_size,
                              hipStream_t stream) {
    const float* x = (const float*)d_in[0];     // [64,256,512]
    const float* pe = (const float*)d_in[1];    // [8,32]
    const float* W = (const float*)d_in[2];     // [512,1536]
    const float* bq = (const float*)d_in[3];    // [1536]
    float* out = (float*)d_out;                 // [64,256,512]
    char* ws = (char*)d_ws;

    bf16* xb = (bf16*)(ws + 0);          // 16 MiB  [16384][512]
    bf16* wt = (bf16*)(ws + 16777216);   // 1.5 MiB [1536][512]

    cvt_x_kernel<<<4096, 256, 0, stream>>>((const float4*)x, (bf16x8*)xb, M_N * K_N / 8);
    transpose_w<<<dim3(16, 48), 256, 0, stream>>>(W, wt);
    fused_qkv_attn<<<512, 512, 0, stream>>>(xb, wt, bq, pe, out);
}